// Round 11
// baseline (69.296 us; speedup 1.0000x reference)
//
#include <hip/hip_runtime.h>

#define TT 28
#define II 28
#define HH 64
#define OO 10

typedef __attribute__((ext_vector_type(8))) __bf16 bf16x8;
typedef __attribute__((ext_vector_type(4))) float f32x4;

#define MFMA(A, B, C) __builtin_amdgcn_mfma_f32_16x16x32_bf16((A), (B), (C), 0, 0, 0)

struct BF3 { __bf16 b0, b1, b2; };

// 3-way bf16 split: v = b0 + b1 + b2 + O(2^-27 |v|). Defined-behavior casts only.
__device__ __forceinline__ BF3 split3(float v) {
    BF3 r;
    r.b0 = (__bf16)v;
    float r1 = v - (float)r.b0;
    r.b1 = (__bf16)r1;
    float r2 = r1 - (float)r.b1;
    r.b2 = (__bf16)r2;
    return r;
}

// Transposed-recurrence MFMA RNN, PERMUTED row layout (passing r3/r8 structure).
// Numerics: 3-way bf16 operand splits + 6-product MFMA chains (operand error
// ~2^-27; eps_step at the fp32-accumulator floor ~2.5e-7) and the PROVEN ocml
// tanh path (__expf + rcp) from every passing round. Raw v_exp_f32 (r10) is
// several-ulp inaccurate and was the dominant error source — do not use it.
// A-frag tile jt carries W rows j(jt,rho) = 32*(jt>>1) + 8*(rho>>2) + 4*(jt&1) + (rho&3).
// Lane (g,b) ends each step holding th[jt][r] = h[32*(jt>>1)+8g+4*(jt&1)+r], which IS
// its own next-step B-fragment: Bfrag[kb][e] = th[2kb+(e>>2)][e&3]. No LDS, no barriers.
__global__ __launch_bounds__(256, 2) void rnn_mfma8(
    const float* __restrict__ X, const float* __restrict__ W_ih,
    const float* __restrict__ W_hh, const float* __restrict__ b_ih,
    const float* __restrict__ b_hh, const float* __restrict__ W_out,
    const float* __restrict__ b_out, float* __restrict__ out)
{
    const int lane = threadIdx.x & 63;
    const int wave = threadIdx.x >> 6;
    const int m15  = lane & 15;        // batch col for B/C, row-within-tile for A
    const int g    = lane >> 4;        // k-group / C row-group
    const int bglob = blockIdx.x * 64 + wave * 16 + m15;
    const int rowhi = 8 * (m15 >> 2) + (m15 & 3);   // permuted-row component

    // ---- W_hh A-fragments, 3-way split, permuted rows ----
    bf16x8 whh0[4][2], whh1[4][2], whh2[4][2];
    #pragma unroll
    for (int jt = 0; jt < 4; ++jt) {
        const int jA = 32 * (jt >> 1) + 4 * (jt & 1) + rowhi;
        #pragma unroll
        for (int kb = 0; kb < 2; ++kb) {
            const float* p = W_hh + jA * HH + 32 * kb + 8 * g;
            float4 a = *(const float4*)p;
            float4 c = *(const float4*)(p + 4);
            float w[8] = {a.x, a.y, a.z, a.w, c.x, c.y, c.z, c.w};
            #pragma unroll
            for (int e = 0; e < 8; ++e) {
                BF3 s = split3(w[e]);
                whh0[jt][kb][e] = s.b0;
                whh1[jt][kb][e] = s.b1;
                whh2[jt][kb][e] = s.b2;
            }
        }
    }

    // ---- W_ih A-fragments, K padded to 32 (k=28 carries bias), 3-way split ----
    bf16x8 wih0[4], wih1[4], wih2[4];
    #pragma unroll
    for (int jt = 0; jt < 4; ++jt) {
        const int jA = 32 * (jt >> 1) + 4 * (jt & 1) + rowhi;
        #pragma unroll
        for (int e = 0; e < 8; ++e) {
            int k = 8 * g + e;
            float v = 0.f;
            if (k < II)       v = W_ih[jA * II + k];
            else if (k == II) v = b_ih[jA] + b_hh[jA];
            BF3 s = split3(v);
            wih0[jt][e] = s.b0;
            wih1[jt][e] = s.b1;
            wih2[jt][e] = s.b2;
        }
    }

    const float* xbase = X + (size_t)bglob * (TT * II);

    // prefetch x for t=0 (k=28 is the bias column: x28 = 1)
    float4 xr0, xr1;
    {
        const float* p = xbase + 8 * g;
        xr0 = *(const float4*)p;
        xr1 = (g < 3) ? *(const float4*)(p + 4) : make_float4(1.f, 0.f, 0.f, 0.f);
    }

    bf16x8 h0[2], h1[2], h2[2];   // h B-fragments (3-way), valid for t>=1
    float th[4][4];

    for (int t = 0; t < TT; ++t) {
        // ---- build x B-fragments (3-way split) ----
        float xv[8] = {xr0.x, xr0.y, xr0.z, xr0.w, xr1.x, xr1.y, xr1.z, xr1.w};
        bf16x8 xs0, xs1, xs2;
        #pragma unroll
        for (int e = 0; e < 8; ++e) {
            BF3 s = split3(xv[e]);
            xs0[e] = s.b0; xs1[e] = s.b1; xs2[e] = s.b2;
        }

        // prefetch next t
        if (t < TT - 1) {
            const float* p = xbase + (t + 1) * II + 8 * g;
            xr0 = *(const float4*)p;
            xr1 = (g < 3) ? *(const float4*)(p + 4) : make_float4(1.f, 0.f, 0.f, 0.f);
        }

        // ---- per tile: x-proj chain (6 products) + recurrent chain (2x6) ----
        #pragma unroll
        for (int jt = 0; jt < 4; ++jt) {
            f32x4 aX = {0.f, 0.f, 0.f, 0.f};
            aX = MFMA(wih0[jt], xs0, aX);
            aX = MFMA(wih0[jt], xs1, aX);
            aX = MFMA(wih1[jt], xs0, aX);
            aX = MFMA(wih0[jt], xs2, aX);
            aX = MFMA(wih1[jt], xs1, aX);
            aX = MFMA(wih2[jt], xs0, aX);
            if (t > 0) {
                f32x4 aH = {0.f, 0.f, 0.f, 0.f};
                #pragma unroll
                for (int kb = 0; kb < 2; ++kb) {
                    aH = MFMA(whh0[jt][kb], h0[kb], aH);
                    aH = MFMA(whh0[jt][kb], h1[kb], aH);
                    aH = MFMA(whh1[jt][kb], h0[kb], aH);
                    aH = MFMA(whh0[jt][kb], h2[kb], aH);
                    aH = MFMA(whh1[jt][kb], h1[kb], aH);
                    aH = MFMA(whh2[jt][kb], h0[kb], aH);
                }
                aX = aX + aH;
            }
            // ---- tanh: PROVEN ocml path (bit-identical to r1/r2/r3/r8) ----
            #pragma unroll
            for (int r = 0; r < 4; ++r) {
                float aa = aX[r];
                float e = __expf(2.f * aa);
                th[jt][r] = 1.f - 2.f * __builtin_amdgcn_rcpf(e + 1.f);
            }
        }

        // ---- build next-step h B-fragments: purely lane-local, 3-way split ----
        if (t < TT - 1) {
            #pragma unroll
            for (int kb = 0; kb < 2; ++kb) {
                #pragma unroll
                for (int e = 0; e < 8; ++e) {
                    float v = th[2 * kb + (e >> 2)][e & 3];
                    BF3 s = split3(v);
                    h0[kb][e] = s.b0; h1[kb][e] = s.b1; h2[kb][e] = s.b2;
                }
            }
        }
    }

    // ---- output head: out[b,o] = h . W_out[o,:] + b_out[o] (permuted j) ----
    float po[OO];
    #pragma unroll
    for (int o = 0; o < OO; ++o) {
        float s = 0.f;
        #pragma unroll
        for (int jt = 0; jt < 4; ++jt) {
            const float* wp = W_out + o * HH + 32 * (jt >> 1) + 8 * g + 4 * (jt & 1);
            float4 wv = *(const float4*)wp;
            s += th[jt][0] * wv.x + th[jt][1] * wv.y +
                 th[jt][2] * wv.z + th[jt][3] * wv.w;
        }
        s += __shfl_xor(s, 16);
        s += __shfl_xor(s, 32);
        po[o] = s;
    }
    if (g == 0) {
        #pragma unroll
        for (int o = 0; o < OO; ++o)
            out[(size_t)bglob * OO + o] = po[o] + b_out[o];
    }
}

extern "C" void kernel_launch(void* const* d_in, const int* in_sizes, int n_in,
                              void* d_out, int out_size, void* d_ws, size_t ws_size,
                              hipStream_t stream) {
    const float* X     = (const float*)d_in[0];
    const float* W_ih  = (const float*)d_in[1];
    const float* W_hh  = (const float*)d_in[2];
    const float* b_ih  = (const float*)d_in[3];
    const float* b_hh  = (const float*)d_in[4];
    const float* W_out = (const float*)d_in[5];
    const float* b_out = (const float*)d_in[6];
    float* out = (float*)d_out;

    const int B = in_sizes[0] / (TT * II);   // 32768
    dim3 grid(B / 64), block(256);           // 4 waves x 16 batch elems per block
    hipLaunchKernelGGL(rnn_mfma8, grid, block, 0, stream,
                       X, W_ih, W_hh, b_ih, b_hh, W_out, b_out, out);
}

// Round 13
// 68.986 us; speedup vs baseline: 1.0045x; 1.0045x over previous
//
#include <hip/hip_runtime.h>

#define TT 28
#define II 28
#define HH 64
#define OO 10

typedef __attribute__((ext_vector_type(8))) __bf16 bf16x8;
typedef __attribute__((ext_vector_type(2))) __bf16 bf16x2;
typedef __attribute__((ext_vector_type(4))) float f32x4;
typedef __attribute__((ext_vector_type(4))) unsigned int u32x4;

#define MFMA(A, B, C) __builtin_amdgcn_mfma_f32_16x16x32_bf16((A), (B), (C), 0, 0, 0)

__device__ __forceinline__ unsigned cvtpk(float lo, float hi) {
    bf16x2 p; p.x = (__bf16)lo; p.y = (__bf16)hi;   // v_cvt_pk_bf16_f32 (RTNE)
    return __builtin_bit_cast(unsigned, p);
}

struct PK3 { unsigned p0, p1, p2; };
// 3-limb bf16 pair split: (a,b) -> 3 packed bf16 pairs; residuals exact, total
// representation error O(2^-27). Same values as scalar casts (both RTNE), but
// ~3x fewer VALU instrs and the result is already in B-fragment register layout.
__device__ __forceinline__ PK3 split3pk(float a, float b) {
    PK3 r;
    r.p0 = cvtpk(a, b);
    float a0 = __builtin_bit_cast(float, r.p0 << 16);
    float b0 = __builtin_bit_cast(float, r.p0 & 0xFFFF0000u);
    float ra = a - a0, rb = b - b0;
    r.p1 = cvtpk(ra, rb);
    float a1 = __builtin_bit_cast(float, r.p1 << 16);
    float b1 = __builtin_bit_cast(float, r.p1 & 0xFFFF0000u);
    r.p2 = cvtpk(ra - a1, rb - b1);
    return r;
}
__device__ __forceinline__ bf16x8 asbf(u32x4 u) {
    return __builtin_bit_cast(bf16x8, u);
}

// Transposed-recurrence MFMA RNN, PERMUTED row layout — the r11 kernel (passed,
// absmax 0.00195 = fp32 floor) with pair-packed cvt_pk limb construction.
// SINGLE-WAVE ONLY: 4 independent j-split attempts failed; no LDS, no barriers.
// A-frag tile jt carries W rows j(jt,rho) = 32*(jt>>1) + 8*(rho>>2) + 4*(jt&1) + (rho&3).
// Lane (g,b) ends each step holding th[jt][r] = h[32*(jt>>1)+8g+4*(jt&1)+r], which IS
// its own next-step B-fragment: Bfrag[kb][e] = th[2kb+(e>>2)][e&3].
// tanh: proven ocml __expf path (raw v_exp_f32 is NOT accurate enough — r10).
__global__ __launch_bounds__(256, 2) void rnn_mfma10(
    const float* __restrict__ X, const float* __restrict__ W_ih,
    const float* __restrict__ W_hh, const float* __restrict__ b_ih,
    const float* __restrict__ b_hh, const float* __restrict__ W_out,
    const float* __restrict__ b_out, float* __restrict__ out)
{
    const int lane = threadIdx.x & 63;
    const int wave = threadIdx.x >> 6;
    const int m15  = lane & 15;        // batch col for B/C, row-within-tile for A
    const int g    = lane >> 4;        // k-group / C row-group
    const int bglob = blockIdx.x * 64 + wave * 16 + m15;
    const int rowhi = 8 * (m15 >> 2) + (m15 & 3);   // permuted-row component

    // ---- W_hh A-fragments, 3-limb, permuted rows ----
    bf16x8 whh0[4][2], whh1[4][2], whh2[4][2];
    #pragma unroll
    for (int jt = 0; jt < 4; ++jt) {
        const int jA = 32 * (jt >> 1) + 4 * (jt & 1) + rowhi;
        #pragma unroll
        for (int kb = 0; kb < 2; ++kb) {
            const float* p = W_hh + jA * HH + 32 * kb + 8 * g;
            float4 a = *(const float4*)p;
            float4 c = *(const float4*)(p + 4);
            u32x4 u0, u1, u2;
            PK3 s;
            s = split3pk(a.x, a.y); u0.x = s.p0; u1.x = s.p1; u2.x = s.p2;
            s = split3pk(a.z, a.w); u0.y = s.p0; u1.y = s.p1; u2.y = s.p2;
            s = split3pk(c.x, c.y); u0.z = s.p0; u1.z = s.p1; u2.z = s.p2;
            s = split3pk(c.z, c.w); u0.w = s.p0; u1.w = s.p1; u2.w = s.p2;
            whh0[jt][kb] = asbf(u0); whh1[jt][kb] = asbf(u1); whh2[jt][kb] = asbf(u2);
        }
    }

    // ---- W_ih A-fragments, K padded to 32 (k=28 carries bias), 3-limb ----
    bf16x8 wih0[4], wih1[4], wih2[4];
    #pragma unroll
    for (int jt = 0; jt < 4; ++jt) {
        const int jA = 32 * (jt >> 1) + 4 * (jt & 1) + rowhi;
        float wv[8];
        #pragma unroll
        for (int e = 0; e < 8; ++e) {
            int k = 8 * g + e;
            float v = 0.f;
            if (k < II)       v = W_ih[jA * II + k];
            else if (k == II) v = b_ih[jA] + b_hh[jA];
            wv[e] = v;
        }
        u32x4 u0, u1, u2;
        PK3 s;
        s = split3pk(wv[0], wv[1]); u0.x = s.p0; u1.x = s.p1; u2.x = s.p2;
        s = split3pk(wv[2], wv[3]); u0.y = s.p0; u1.y = s.p1; u2.y = s.p2;
        s = split3pk(wv[4], wv[5]); u0.z = s.p0; u1.z = s.p1; u2.z = s.p2;
        s = split3pk(wv[6], wv[7]); u0.w = s.p0; u1.w = s.p1; u2.w = s.p2;
        wih0[jt] = asbf(u0); wih1[jt] = asbf(u1); wih2[jt] = asbf(u2);
    }

    const float* xbase = X + (size_t)bglob * (TT * II);

    // prefetch x for t=0 (k=28 is the bias column: x28 = 1)
    float4 xr0, xr1;
    {
        const float* p = xbase + 8 * g;
        xr0 = *(const float4*)p;
        xr1 = (g < 3) ? *(const float4*)(p + 4) : make_float4(1.f, 0.f, 0.f, 0.f);
    }

    bf16x8 h0[2], h1[2], h2[2];   // h B-fragments (3-limb), valid for t>=1
    float th[4][4];

    for (int t = 0; t < TT; ++t) {
        // ---- x B-fragments (3-limb, pair-packed) ----
        bf16x8 xs0, xs1, xs2;
        {
            u32x4 u0, u1, u2;
            PK3 s;
            s = split3pk(xr0.x, xr0.y); u0.x = s.p0; u1.x = s.p1; u2.x = s.p2;
            s = split3pk(xr0.z, xr0.w); u0.y = s.p0; u1.y = s.p1; u2.y = s.p2;
            s = split3pk(xr1.x, xr1.y); u0.z = s.p0; u1.z = s.p1; u2.z = s.p2;
            s = split3pk(xr1.z, xr1.w); u0.w = s.p0; u1.w = s.p1; u2.w = s.p2;
            xs0 = asbf(u0); xs1 = asbf(u1); xs2 = asbf(u2);
        }

        // prefetch next t
        if (t < TT - 1) {
            const float* p = xbase + (t + 1) * II + 8 * g;
            xr0 = *(const float4*)p;
            xr1 = (g < 3) ? *(const float4*)(p + 4) : make_float4(1.f, 0.f, 0.f, 0.f);
        }

        // ---- per tile: x-proj chain (6 products) + recurrent chain (2x6) ----
        #pragma unroll
        for (int jt = 0; jt < 4; ++jt) {
            f32x4 aX = {0.f, 0.f, 0.f, 0.f};
            aX = MFMA(wih0[jt], xs0, aX);
            aX = MFMA(wih0[jt], xs1, aX);
            aX = MFMA(wih1[jt], xs0, aX);
            aX = MFMA(wih0[jt], xs2, aX);
            aX = MFMA(wih1[jt], xs1, aX);
            aX = MFMA(wih2[jt], xs0, aX);
            if (t > 0) {
                f32x4 aH = {0.f, 0.f, 0.f, 0.f};
                #pragma unroll
                for (int kb = 0; kb < 2; ++kb) {
                    aH = MFMA(whh0[jt][kb], h0[kb], aH);
                    aH = MFMA(whh0[jt][kb], h1[kb], aH);
                    aH = MFMA(whh1[jt][kb], h0[kb], aH);
                    aH = MFMA(whh0[jt][kb], h2[kb], aH);
                    aH = MFMA(whh1[jt][kb], h1[kb], aH);
                    aH = MFMA(whh2[jt][kb], h0[kb], aH);
                }
                aX = aX + aH;
            }
            // ---- tanh: PROVEN ocml path ----
            #pragma unroll
            for (int r = 0; r < 4; ++r) {
                float aa = aX[r];
                float e = __expf(2.f * aa);
                th[jt][r] = 1.f - 2.f * __builtin_amdgcn_rcpf(e + 1.f);
            }
        }

        // ---- next-step h B-fragments: lane-local, 3-limb, pair-packed ----
        if (t < TT - 1) {
            #pragma unroll
            for (int kb = 0; kb < 2; ++kb) {
                u32x4 u0, u1, u2;
                PK3 s;
                s = split3pk(th[2 * kb][0], th[2 * kb][1]);
                u0.x = s.p0; u1.x = s.p1; u2.x = s.p2;
                s = split3pk(th[2 * kb][2], th[2 * kb][3]);
                u0.y = s.p0; u1.y = s.p1; u2.y = s.p2;
                s = split3pk(th[2 * kb + 1][0], th[2 * kb + 1][1]);
                u0.z = s.p0; u1.z = s.p1; u2.z = s.p2;
                s = split3pk(th[2 * kb + 1][2], th[2 * kb + 1][3]);
                u0.w = s.p0; u1.w = s.p1; u2.w = s.p2;
                h0[kb] = asbf(u0); h1[kb] = asbf(u1); h2[kb] = asbf(u2);
            }
        }
    }

    // ---- output head: out[b,o] = h . W_out[o,:] + b_out[o] (permuted j) ----
    float po[OO];
    #pragma unroll
    for (int o = 0; o < OO; ++o) {
        float s = 0.f;
        #pragma unroll
        for (int jt = 0; jt < 4; ++jt) {
            const float* wp = W_out + o * HH + 32 * (jt >> 1) + 8 * g + 4 * (jt & 1);
            float4 wv = *(const float4*)wp;
            s += th[jt][0] * wv.x + th[jt][1] * wv.y +
                 th[jt][2] * wv.z + th[jt][3] * wv.w;
        }
        s += __shfl_xor(s, 16);
        s += __shfl_xor(s, 32);
        po[o] = s;
    }
    if (g == 0) {
        #pragma unroll
        for (int o = 0; o < OO; ++o)
            out[(size_t)bglob * OO + o] = po[o] + b_out[o];
    }
}

extern "C" void kernel_launch(void* const* d_in, const int* in_sizes, int n_in,
                              void* d_out, int out_size, void* d_ws, size_t ws_size,
                              hipStream_t stream) {
    const float* X     = (const float*)d_in[0];
    const float* W_ih  = (const float*)d_in[1];
    const float* W_hh  = (const float*)d_in[2];
    const float* b_ih  = (const float*)d_in[3];
    const float* b_hh  = (const float*)d_in[4];
    const float* W_out = (const float*)d_in[5];
    const float* b_out = (const float*)d_in[6];
    float* out = (float*)d_out;

    const int B = in_sizes[0] / (TT * II);   // 32768
    dim3 grid(B / 64), block(256);           // 4 waves x 16 batch elems per block
    hipLaunchKernelGGL(rnn_mfma10, grid, block, 0, stream,
                       X, W_ih, W_hh, b_ih, b_hh, W_out, b_out, out);
}